// Round 3
// baseline (9341.819 us; speedup 1.0000x reference)
//
#include <hip/hip_runtime.h>
#include <math.h>

typedef _Float16 f16;
typedef _Float16 f16x8 __attribute__((ext_vector_type(8)));
typedef float f32x4 __attribute__((ext_vector_type(4)));

#define B_TOTAL 4096
#define T_STEPS 128
#define H 96
#define NB 16            // batch rows per block
#define NTH 384          // 6 waves
#define NBPL (B_TOTAL / NB)   // 256 blocks per layer
#define FLAG_STRIDE 16   // ints; one 64B line per flag

__device__ __forceinline__ float sigf(float v) { return 1.f / (1.f + __expf(-v)); }
__device__ __forceinline__ float tanhf_(float v) { float e = __expf(2.f * v); return 1.f - 2.f / (e + 1.f); }

// One LSTM layer, persistent over all T, weights VGPR-resident as MFMA B-frags.
// Fused pipeline: consumer waits flag_in >= t+1 before staging ys[t]; producer
// sets flag_out = t+1 (release, agent scope) after its ys[t] stores are drained
// by the preceding __syncthreads(). ys is an in-place relay buffer.
template<int F, bool IS_L0, bool HAS_YSOUT>
__device__ __forceinline__ void layer_body(
    char* smbase,
    const float* __restrict__ x32,   // IS_L0 only: x [B][T][F]
    f16*  __restrict__ ys,           // relay [T][B][H] f16
    const float* __restrict__ Wi, const float* __restrict__ Wh,
    const float* __restrict__ bi, const float* __restrict__ bh,
    float* __restrict__ hnout,       // may be null
    int* flag_in, int* flag_out, int b)
{
    constexpr int KS  = (F + H + 31) / 32;   // 4 (F=24) or 6 (F=96)
    constexpr int KP  = KS * 32;
    constexpr int KPB = KP * 2;

    f16* smh = (f16*)smbase;
    f16* sml = (f16*)(smbase + NB * KPB);

    const int tid  = threadIdx.x;
    const int lane = tid & 63;
    const int w    = tid >> 6;      // wave -> unit group
    const int j15  = lane & 15;
    const int g4   = lane >> 4;
    const int u    = 16 * w + j15;  // unit 0..95
    const int row0 = b * NB;

    for (int i = tid; i < NB * KP; i += NTH) { smh[i] = (f16)0.f; sml[i] = (f16)0.f; }

    // weight B-frags, loaded once: lane holds W[j=96q+u][k=32s+8*g4+e]
    f16x8 Bf[4][KS];
#pragma unroll
    for (int q = 0; q < 4; ++q) {
        const int j = 96 * q + u;
#pragma unroll
        for (int s = 0; s < KS; ++s) {
            f16x8 f;
#pragma unroll
            for (int e = 0; e < 8; ++e) {
                int k = 32 * s + 8 * g4 + e;
                float v = 0.f;
                if (k < F)          v = Wi[(size_t)j * F + k];
                else if (k - F < H) v = Wh[(size_t)j * H + (k - F)];
                f[e] = (f16)v;
            }
            Bf[q][s] = f;
        }
    }
    float bq[4];
#pragma unroll
    for (int q = 0; q < 4; ++q) bq[q] = bi[96 * q + u] + bh[96 * q + u];

    float c4[4] = {0.f, 0.f, 0.f, 0.f};

    auto spin_ge = [&](int v) {
        if (!IS_L0)
            while (__hip_atomic_load(flag_in, __ATOMIC_ACQUIRE, __HIP_MEMORY_SCOPE_AGENT) < v)
                __builtin_amdgcn_s_sleep(2);
    };
    auto stage = [&](int tt) {
        if constexpr (IS_L0) {
            // 16 rows x 24 feats = 384 threads: one fp32 each, hi/lo split
            int r = tid / F, k = tid - r * F;
            float v = x32[(size_t)(row0 + r) * (T_STEPS * F) + (size_t)tt * F + k];
            f16 vh = (f16)v; f16 vl = (f16)(v - (float)vh);
            int off = r * KPB + ((k * 2) ^ ((r & 7) << 4));
            *(f16*)((char*)smh + off) = vh;
            *(f16*)((char*)sml + off) = vl;
        } else {
            // 16 rows x 96 halves: 8B per thread (lo input region stays 0)
            int idx = tid * 4;
            int r = idx / H, k0 = idx - r * H;
            uint2 v = *(const uint2*)(ys + ((size_t)tt * B_TOTAL + row0 + r) * H + k0);
            int off = r * KPB + ((k0 * 2) ^ ((r & 7) << 4));
            *(uint2*)((char*)smh + off) = v;
        }
    };

    __syncthreads();
    spin_ge(1);
    stage(0);
    __syncthreads();

    const int abase = j15 * KPB;
    const int aswz  = (j15 & 7) << 4;

#pragma unroll 1
    for (int t = 0; t < T_STEPS; ++t) {
        // two accumulator chains (hi/lo) halve the MFMA dependency depth
        f32x4 acch[4], accl[4];
#pragma unroll
        for (int q = 0; q < 4; ++q) {
            f32x4 ah = {bq[q], bq[q], bq[q], bq[q]}; acch[q] = ah;
            f32x4 al = {0.f, 0.f, 0.f, 0.f};          accl[q] = al;
        }
#pragma unroll
        for (int s = 0; s < KS; ++s) {
            int kb = ((s * 64 + g4 * 16) ^ aswz);
            f16x8 ah = *(const f16x8*)((const char*)smh + abase + kb);
            f16x8 al = *(const f16x8*)((const char*)sml + abase + kb);
#pragma unroll
            for (int q = 0; q < 4; ++q)
                acch[q] = __builtin_amdgcn_mfma_f32_16x16x32_f16(ah, Bf[q][s], acch[q], 0, 0, 0);
#pragma unroll
            for (int q = 0; q < 4; ++q)
                accl[q] = __builtin_amdgcn_mfma_f32_16x16x32_f16(al, Bf[q][s], accl[q], 0, 0, 0);
        }
        __syncthreads();   // A: MFMA reads done before h-region overwrite

        // C[row][col]: col=lane&15 (unit), row=(lane>>4)*4+reg
#pragma unroll
        for (int r = 0; r < 4; ++r) {
            float iv = sigf(acch[0][r] + accl[0][r]);
            float fv = sigf(acch[1][r] + accl[1][r]);
            float gv = tanhf_(acch[2][r] + accl[2][r]);
            float ov = sigf(acch[3][r] + accl[3][r]);
            float c  = fv * c4[r] + iv * gv;
            c4[r] = c;
            float h = ov * tanhf_(c);
            int row = 4 * g4 + r;
            f16 hh = (f16)h;
            f16 hl = (f16)(h - (float)hh);
            int off = row * KPB + (((F + u) * 2) ^ ((row & 7) << 4));
            *(f16*)((char*)smh + off) = hh;
            *(f16*)((char*)sml + off) = hl;
            if (HAS_YSOUT) ys[((size_t)t * B_TOTAL + row0 + row) * H + u] = hh;
            if (hnout && t == T_STEPS - 1) hnout[(size_t)(row0 + row) * H + u] = h;
        }
        if (t + 1 < T_STEPS) { spin_ge(t + 2); stage(t + 1); }
        __syncthreads();   // B: h/stage LDS writes + ys global stores drained
        if (HAS_YSOUT && tid == 0)
            __hip_atomic_store(flag_out, t + 1, __ATOMIC_RELEASE, __HIP_MEMORY_SCOPE_AGENT);
    }
}

__global__ __launch_bounds__(NTH, 6)
void lstm_fused(const float* __restrict__ x,
                const float* __restrict__ W_ih0,
                const float* __restrict__ W_ih_rest,
                const float* __restrict__ W_hh,
                const float* __restrict__ b_ih,
                const float* __restrict__ b_hh,
                f16* __restrict__ ys, float* __restrict__ hn1, float* __restrict__ hn3,
                int* __restrict__ flags)
{
    extern __shared__ char smbase[];
    const int l = blockIdx.x >> 8;
    const int b = blockIdx.x & 255;
    const int GH = 384 * 96;
    int* f0 = flags + (0 * NBPL + b) * FLAG_STRIDE;
    int* f1 = flags + (1 * NBPL + b) * FLAG_STRIDE;
    int* f2 = flags + (2 * NBPL + b) * FLAG_STRIDE;

    if (l == 0)
        layer_body<24, true,  true >(smbase, x, ys, W_ih0,             W_hh,          b_ih,           b_hh,           nullptr, nullptr, f0, b);
    else if (l == 1)
        layer_body<96, false, true >(smbase, nullptr, ys, W_ih_rest,          W_hh + 1 * GH, b_ih + 1 * 384, b_hh + 1 * 384, hn1,     f0, f1, b);
    else if (l == 2)
        layer_body<96, false, true >(smbase, nullptr, ys, W_ih_rest + 1 * GH, W_hh + 2 * GH, b_ih + 2 * 384, b_hh + 2 * 384, nullptr, f1, f2, b);
    else
        layer_body<96, false, false>(smbase, nullptr, ys, W_ih_rest + 2 * GH, W_hh + 3 * GH, b_ih + 3 * 384, b_hh + 3 * 384, hn3,    f2, nullptr, b);
}

__global__ __launch_bounds__(256)
void head_kernel(const float* __restrict__ hn1, const float* __restrict__ hn3,
                 const float* __restrict__ fc1_w, const float* __restrict__ fc1_b,
                 const float* __restrict__ fc2_w, const float* __restrict__ fc2_b,
                 const float* __restrict__ fc3_w, const float* __restrict__ fc3_b,
                 float* __restrict__ out)
{
    int b = blockIdx.x * blockDim.x + threadIdx.x;
    if (b >= B_TOTAL) return;
    float z1[16];
#pragma unroll
    for (int j = 0; j < 16; ++j) z1[j] = fc1_b[j];
    for (int uu = 0; uu < H; ++uu) {
        float s = hn1[(size_t)b * H + uu] + hn3[(size_t)b * H + uu];
        s = fmaxf(s, 0.f);
#pragma unroll
        for (int j = 0; j < 16; ++j) z1[j] += fc1_w[j * H + uu] * s;
    }
#pragma unroll
    for (int j = 0; j < 16; ++j) z1[j] = fmaxf(z1[j], 0.f);
    float z2[8];
#pragma unroll
    for (int j = 0; j < 8; ++j) {
        float a = fc2_b[j];
#pragma unroll
        for (int uu = 0; uu < 16; ++uu) a += fc2_w[j * 16 + uu] * z1[uu];
        z2[j] = fmaxf(a, 0.f);
    }
    float a = fc3_b[0];
#pragma unroll
    for (int uu = 0; uu < 8; ++uu) a += fc3_w[uu] * z2[uu];
    out[b] = a;
}

extern "C" void kernel_launch(void* const* d_in, const int* in_sizes, int n_in,
                              void* d_out, int out_size, void* d_ws, size_t ws_size,
                              hipStream_t stream) {
    const float* x         = (const float*)d_in[0];
    const float* W_ih0     = (const float*)d_in[1];
    const float* W_ih_rest = (const float*)d_in[2];
    const float* W_hh      = (const float*)d_in[3];
    const float* b_ih      = (const float*)d_in[4];
    const float* b_hh      = (const float*)d_in[5];
    const float* fc1_w     = (const float*)d_in[6];
    const float* fc1_b     = (const float*)d_in[7];
    const float* fc2_w     = (const float*)d_in[8];
    const float* fc2_b     = (const float*)d_in[9];
    const float* fc3_w     = (const float*)d_in[10];
    const float* fc3_b     = (const float*)d_in[11];
    float* out = (float*)d_out;

    const size_t YS = (size_t)T_STEPS * B_TOTAL * H * sizeof(f16);   // ~100.7 MB
    const size_t HN = (size_t)B_TOTAL * H * sizeof(float);           // ~1.6 MB
    const size_t FL = (size_t)3 * NBPL * FLAG_STRIDE * sizeof(int);  // 48 KB
    if (ws_size < YS + 2 * HN + FL) {
        hipMemsetAsync(d_out, 0, (size_t)out_size * sizeof(float), stream);
        return;
    }
    f16*   ys    = (f16*)d_ws;
    float* hn1   = (float*)((char*)d_ws + YS);
    float* hn3   = hn1 + (size_t)B_TOTAL * H;
    int*   flags = (int*)((char*)d_ws + YS + 2 * HN);

    hipMemsetAsync(flags, 0, FL, stream);

    lstm_fused<<<dim3(4 * NBPL), dim3(NTH), 12288, stream>>>(
        x, W_ih0, W_ih_rest, W_hh, b_ih, b_hh, ys, hn1, hn3, flags);

    head_kernel<<<(B_TOTAL + 255) / 256, 256, 0, stream>>>(
        hn1, hn3, fc1_w, fc1_b, fc2_w, fc2_b, fc3_w, fc3_b, out);
}

// Round 4
// 4858.002 us; speedup vs baseline: 1.9230x; 1.9230x over previous
//
#include <hip/hip_runtime.h>
#include <math.h>

typedef _Float16 f16;
typedef _Float16 f16x8 __attribute__((ext_vector_type(8)));
typedef float f32x4 __attribute__((ext_vector_type(4)));

#define B_TOTAL 4096
#define T_STEPS 128
#define H 96
#define NB 32                 // batch rows per block (2 MFMA m-tiles)
#define NTH 384               // 6 waves
#define NBPL (B_TOTAL / NB)   // 128 blocks per layer; 4*128 = 512 = 2 blocks/CU
#define FLAG_STRIDE 16        // ints; one 64B line per flag
#define SM_BYTES 24576        // 2 planes * 32 rows * 192 * 2B (max KP)

__device__ __forceinline__ float sigf(float v) { return 1.f / (1.f + __expf(-v)); }
__device__ __forceinline__ float tanhf_(float v) { float e = __expf(2.f * v); return 1.f - 2.f / (e + 1.f); }

// One LSTM layer, persistent over all T, weights VGPR-resident as MFMA B-frags.
// 4-layer software pipeline across blocks; flags carry release/acquire (agent
// scope) producer->consumer sync per (link, batch-tile). ys is an in-place
// relay buffer [T][B][H] f16.
// LO_S0: first k-slice of the lo (residual) activation plane; input-region
// slices of layers 1..3 are exactly zero (ys is pure f16) and are skipped.
template<int F, int LO_S0, bool IS_L0, bool HAS_YSOUT>
__device__ __forceinline__ void layer_body(
    char* smbase,
    const float* __restrict__ x32,
    f16*  __restrict__ ys,
    const float* __restrict__ Wi, const float* __restrict__ Wh,
    const float* __restrict__ bi, const float* __restrict__ bh,
    float* __restrict__ hnout,
    int* flag_in, int* flag_out, int b)
{
    constexpr int KS  = (F + H + 31) / 32;   // 4 (F=24) or 6 (F=96)
    constexpr int KP  = KS * 32;
    constexpr int KPB = KP * 2;

    f16* smh = (f16*)smbase;
    f16* sml = (f16*)(smbase + NB * KPB);

    const int tid  = threadIdx.x;
    const int lane = tid & 63;
    const int w    = tid >> 6;      // wave -> unit group
    const int j15  = lane & 15;
    const int g4   = lane >> 4;
    const int u    = 16 * w + j15;  // unit 0..95
    const int row0 = b * NB;

    for (int i = tid; i < NB * KP; i += NTH) { smh[i] = (f16)0.f; sml[i] = (f16)0.f; }

    // weight B-frags, loaded once: lane holds W[j=96q+u][k=32s+8*g4+e]
    f16x8 Bf[4][KS];
#pragma unroll
    for (int q = 0; q < 4; ++q) {
        const int j = 96 * q + u;
#pragma unroll
        for (int s = 0; s < KS; ++s) {
            f16x8 f;
#pragma unroll
            for (int e = 0; e < 8; ++e) {
                int k = 32 * s + 8 * g4 + e;
                float v = 0.f;
                if (k < F)          v = Wi[(size_t)j * F + k];
                else if (k - F < H) v = Wh[(size_t)j * H + (k - F)];
                f[e] = (f16)v;
            }
            Bf[q][s] = f;
        }
    }
    float bq[4];
#pragma unroll
    for (int q = 0; q < 4; ++q) bq[q] = bi[96 * q + u] + bh[96 * q + u];

    float c4[2][4] = {{0.f,0.f,0.f,0.f},{0.f,0.f,0.f,0.f}};

    auto spin_ge = [&](int v) {
        if (!IS_L0)
            while (__hip_atomic_load(flag_in, __ATOMIC_ACQUIRE, __HIP_MEMORY_SCOPE_AGENT) < v)
                __builtin_amdgcn_s_sleep(2);
    };
    auto stage = [&](int tt) {
        if constexpr (IS_L0) {
            // 32 rows x 24 feats = 768 fp32; 2 per thread, hi/lo split
#pragma unroll
            for (int ii = 0; ii < 2; ++ii) {
                int i = tid * 2 + ii;
                int r = i / F, k = i - r * F;
                float v = x32[(size_t)(row0 + r) * (T_STEPS * F) + (size_t)tt * F + k];
                f16 vh = (f16)v; f16 vl = (f16)(v - (float)vh);
                int off = r * KPB + ((k * 2) ^ ((r & 7) << 4));
                *(f16*)((char*)smh + off) = vh;
                *(f16*)((char*)sml + off) = vl;
            }
        } else {
            // 32 rows x 96 halves = 6144B; one uint4 (8 halves) per thread
            int idx = tid * 8;
            int r = idx / H, k0 = idx - r * H;
            uint4 v = *(const uint4*)(ys + ((size_t)tt * B_TOTAL + row0 + r) * H + k0);
            int off = r * KPB + ((k0 * 2) ^ ((r & 7) << 4));
            *(uint4*)((char*)smh + off) = v;
        }
    };

    __syncthreads();
    spin_ge(1);
    stage(0);
    __syncthreads();

    const int aswz = (j15 & 7) << 4;

#pragma unroll 1
    for (int t = 0; t < T_STEPS; ++t) {
        float h4[2][4];
        // ---- MFMA + register-local cell update, per m-tile (frees acc early) ----
#pragma unroll
        for (int m = 0; m < 2; ++m) {
            f32x4 acch[4], accl[4];
#pragma unroll
            for (int q = 0; q < 4; ++q) {
                f32x4 a = {bq[q], bq[q], bq[q], bq[q]}; acch[q] = a;
                f32x4 z = {0.f, 0.f, 0.f, 0.f};          accl[q] = z;
            }
            const int abase = (m * 16 + j15) * KPB;
#pragma unroll
            for (int s = 0; s < KS; ++s) {
                int kb = ((s * 64 + g4 * 16) ^ aswz);
                f16x8 ah = *(const f16x8*)((const char*)smh + abase + kb);
#pragma unroll
                for (int q = 0; q < 4; ++q)
                    acch[q] = __builtin_amdgcn_mfma_f32_16x16x32_f16(ah, Bf[q][s], acch[q], 0, 0, 0);
                if (s >= LO_S0) {
                    f16x8 al = *(const f16x8*)((const char*)sml + abase + kb);
#pragma unroll
                    for (int q = 0; q < 4; ++q)
                        accl[q] = __builtin_amdgcn_mfma_f32_16x16x32_f16(al, Bf[q][s], accl[q], 0, 0, 0);
                }
            }
#pragma unroll
            for (int r = 0; r < 4; ++r) {
                float iv = sigf(acch[0][r] + accl[0][r]);
                float fv = sigf(acch[1][r] + accl[1][r]);
                float gv = tanhf_(acch[2][r] + accl[2][r]);
                float ov = sigf(acch[3][r] + accl[3][r]);
                float c  = fv * c4[m][r] + iv * gv;
                c4[m][r] = c;
                h4[m][r] = ov * tanhf_(c);
            }
        }
        __syncthreads();   // all waves' LDS act reads done; h/stage writes may begin

#pragma unroll
        for (int m = 0; m < 2; ++m)
#pragma unroll
        for (int r = 0; r < 4; ++r) {
            int row = m * 16 + 4 * g4 + r;
            float h = h4[m][r];
            f16 hh = (f16)h;
            f16 hl = (f16)(h - (float)hh);
            int off = row * KPB + (((F + u) * 2) ^ ((row & 7) << 4));
            *(f16*)((char*)smh + off) = hh;
            *(f16*)((char*)sml + off) = hl;
            if (HAS_YSOUT) ys[((size_t)t * B_TOTAL + row0 + row) * H + u] = hh;
            if (hnout && t == T_STEPS - 1) hnout[(size_t)(row0 + row) * H + u] = h;
        }
        if (t + 1 < T_STEPS) { spin_ge(t + 2); stage(t + 1); }
        __syncthreads();   // LDS writes + ys stores drained (vmcnt0 before barrier)
        if (HAS_YSOUT && tid == 0)
            __hip_atomic_store(flag_out, t + 1, __ATOMIC_RELEASE, __HIP_MEMORY_SCOPE_AGENT);
    }
}

__global__ __launch_bounds__(NTH, 3)   // 3 waves/EU -> VGPR cap 170; 2 blocks/CU
void lstm_fused(const float* __restrict__ x,
                const float* __restrict__ W_ih0,
                const float* __restrict__ W_ih_rest,
                const float* __restrict__ W_hh,
                const float* __restrict__ b_ih,
                const float* __restrict__ b_hh,
                f16* __restrict__ ys, float* __restrict__ hn1, float* __restrict__ hn3,
                int* __restrict__ flags)
{
    __shared__ char smbase[SM_BYTES];
    const int l = blockIdx.x >> 7;
    const int b = blockIdx.x & (NBPL - 1);
    const int GH = 384 * 96;
    int* f0 = flags + (0 * NBPL + b) * FLAG_STRIDE;
    int* f1 = flags + (1 * NBPL + b) * FLAG_STRIDE;
    int* f2 = flags + (2 * NBPL + b) * FLAG_STRIDE;

    if (l == 0)
        layer_body<24, 0, true,  true >(smbase, x, ys, W_ih0,              W_hh,          b_ih,           b_hh,           nullptr, nullptr, f0, b);
    else if (l == 1)
        layer_body<96, 3, false, true >(smbase, nullptr, ys, W_ih_rest,          W_hh + 1 * GH, b_ih + 1 * 384, b_hh + 1 * 384, hn1,     f0, f1, b);
    else if (l == 2)
        layer_body<96, 3, false, true >(smbase, nullptr, ys, W_ih_rest + 1 * GH, W_hh + 2 * GH, b_ih + 2 * 384, b_hh + 2 * 384, nullptr, f1, f2, b);
    else
        layer_body<96, 3, false, false>(smbase, nullptr, ys, W_ih_rest + 2 * GH, W_hh + 3 * GH, b_ih + 3 * 384, b_hh + 3 * 384, hn3,    f2, nullptr, b);
}

__global__ __launch_bounds__(256)
void head_kernel(const float* __restrict__ hn1, const float* __restrict__ hn3,
                 const float* __restrict__ fc1_w, const float* __restrict__ fc1_b,
                 const float* __restrict__ fc2_w, const float* __restrict__ fc2_b,
                 const float* __restrict__ fc3_w, const float* __restrict__ fc3_b,
                 float* __restrict__ out)
{
    int b = blockIdx.x * blockDim.x + threadIdx.x;
    if (b >= B_TOTAL) return;
    float z1[16];
#pragma unroll
    for (int j = 0; j < 16; ++j) z1[j] = fc1_b[j];
    for (int uu = 0; uu < H; ++uu) {
        float s = hn1[(size_t)b * H + uu] + hn3[(size_t)b * H + uu];
        s = fmaxf(s, 0.f);
#pragma unroll
        for (int j = 0; j < 16; ++j) z1[j] += fc1_w[j * H + uu] * s;
    }
#pragma unroll
    for (int j = 0; j < 16; ++j) z1[j] = fmaxf(z1[j], 0.f);
    float z2[8];
#pragma unroll
    for (int j = 0; j < 8; ++j) {
        float a = fc2_b[j];
#pragma unroll
        for (int uu = 0; uu < 16; ++uu) a += fc2_w[j * 16 + uu] * z1[uu];
        z2[j] = fmaxf(a, 0.f);
    }
    float a = fc3_b[0];
#pragma unroll
    for (int uu = 0; uu < 8; ++uu) a += fc3_w[uu] * z2[uu];
    out[b] = a;
}

extern "C" void kernel_launch(void* const* d_in, const int* in_sizes, int n_in,
                              void* d_out, int out_size, void* d_ws, size_t ws_size,
                              hipStream_t stream) {
    const float* x         = (const float*)d_in[0];
    const float* W_ih0     = (const float*)d_in[1];
    const float* W_ih_rest = (const float*)d_in[2];
    const float* W_hh      = (const float*)d_in[3];
    const float* b_ih      = (const float*)d_in[4];
    const float* b_hh      = (const float*)d_in[5];
    const float* fc1_w     = (const float*)d_in[6];
    const float* fc1_b     = (const float*)d_in[7];
    const float* fc2_w     = (const float*)d_in[8];
    const float* fc2_b     = (const float*)d_in[9];
    const float* fc3_w     = (const float*)d_in[10];
    const float* fc3_b     = (const float*)d_in[11];
    float* out = (float*)d_out;

    const size_t YS = (size_t)T_STEPS * B_TOTAL * H * sizeof(f16);   // ~100.7 MB
    const size_t HN = (size_t)B_TOTAL * H * sizeof(float);           // ~1.6 MB
    const size_t FL = (size_t)3 * NBPL * FLAG_STRIDE * sizeof(int);  // 24 KB
    if (ws_size < YS + 2 * HN + FL) {
        hipMemsetAsync(d_out, 0, (size_t)out_size * sizeof(float), stream);
        return;
    }
    f16*   ys    = (f16*)d_ws;
    float* hn1   = (float*)((char*)d_ws + YS);
    float* hn3   = hn1 + (size_t)B_TOTAL * H;
    int*   flags = (int*)((char*)d_ws + YS + 2 * HN);

    hipMemsetAsync(flags, 0, FL, stream);

    lstm_fused<<<dim3(4 * NBPL), dim3(NTH), 0, stream>>>(
        x, W_ih0, W_ih_rest, W_hh, b_ih, b_hh, ys, hn1, hn3, flags);

    head_kernel<<<(B_TOTAL + 255) / 256, 256, 0, stream>>>(
        hn1, hn3, fc1_w, fc1_b, fc2_w, fc2_b, fc3_w, fc3_b, out);
}

// Round 5
// 4006.607 us; speedup vs baseline: 2.3316x; 1.2125x over previous
//
#include <hip/hip_runtime.h>
#include <math.h>

typedef _Float16 f16;
typedef _Float16 f16x8 __attribute__((ext_vector_type(8)));
typedef float f32x4 __attribute__((ext_vector_type(4)));

#define B_TOTAL 4096
#define T_STEPS 128
#define H 96
#define NB 64                 // batch rows per block (4 MFMA m-tiles)
#define NTH 384               // 6 waves
#define NBPL (B_TOTAL / NB)   // 64 blocks per layer; 4*64 = 256 = 1 block/CU
#define FLAG_STRIDE 16        // ints; one 64B line per flag
#define SM_BYTES 49152        // 2 planes * 64 rows * 192 * 2B (max KP)

__device__ __forceinline__ float sigf(float v) { return 1.f / (1.f + __expf(-v)); }
__device__ __forceinline__ float tanhf_(float v) { float e = __expf(2.f * v); return 1.f - 2.f / (e + 1.f); }

// One LSTM layer, persistent over all T, weights VGPR/AGPR-resident as MFMA
// B-frags. 4-layer software pipeline across blocks; flags carry
// release/acquire (agent scope) producer->consumer sync per (link, batch
// tile). ys is an in-place relay buffer [T][B][H] f16.
// LO_S0: first k-slice where the lo (residual) activation plane is nonzero;
// input-region slices of layers 1..3 are exactly zero (ys is pure f16).
template<int F, int LO_S0, bool IS_L0, bool HAS_YSOUT>
__device__ __forceinline__ void layer_body(
    char* smbase,
    const float* __restrict__ x32,
    f16*  __restrict__ ys,
    const float* __restrict__ Wi, const float* __restrict__ Wh,
    const float* __restrict__ bi, const float* __restrict__ bh,
    float* __restrict__ hnout,
    int* flag_in, int* flag_out, int b)
{
    constexpr int KS  = (F + H + 31) / 32;   // 4 (F=24) or 6 (F=96)
    constexpr int KP  = KS * 32;
    constexpr int KPB = KP * 2;

    f16* smh = (f16*)smbase;
    f16* sml = (f16*)(smbase + NB * KPB);

    const int tid  = threadIdx.x;
    const int lane = tid & 63;
    const int w    = tid >> 6;      // wave -> unit group
    const int j15  = lane & 15;
    const int g4   = lane >> 4;
    const int u    = 16 * w + j15;  // unit 0..95
    const int row0 = b * NB;

    for (int i = tid; i < NB * KP; i += NTH) { smh[i] = (f16)0.f; sml[i] = (f16)0.f; }

    // weight B-frags, loaded once: lane holds W[j=96q+u][k=32s+8*g4+e]
    f16x8 Bf[4][KS];
#pragma unroll
    for (int q = 0; q < 4; ++q) {
        const int j = 96 * q + u;
#pragma unroll
        for (int s = 0; s < KS; ++s) {
            f16x8 f;
#pragma unroll
            for (int e = 0; e < 8; ++e) {
                int k = 32 * s + 8 * g4 + e;
                float v = 0.f;
                if (k < F)          v = Wi[(size_t)j * F + k];
                else if (k - F < H) v = Wh[(size_t)j * H + (k - F)];
                f[e] = (f16)v;
            }
            Bf[q][s] = f;
        }
    }
    float bq[4];
#pragma unroll
    for (int q = 0; q < 4; ++q) bq[q] = bi[96 * q + u] + bh[96 * q + u];

    float c4[4][4];
#pragma unroll
    for (int m = 0; m < 4; ++m)
#pragma unroll
        for (int r = 0; r < 4; ++r) c4[m][r] = 0.f;

    auto spin_ge = [&](int v) {
        if (!IS_L0)
            while (__hip_atomic_load(flag_in, __ATOMIC_ACQUIRE, __HIP_MEMORY_SCOPE_AGENT) < v)
                __builtin_amdgcn_s_sleep(2);
    };
    auto stage = [&](int tt) {
        if constexpr (IS_L0) {
            // 64 rows x 24 feats = 1536 fp32; 4 per thread, stride-NTH (coalesced)
#pragma unroll
            for (int ii = 0; ii < 4; ++ii) {
                int i = tid + ii * NTH;
                int r = i / F, k = i - r * F;
                float v = x32[(size_t)(row0 + r) * (T_STEPS * F) + (size_t)tt * F + k];
                f16 vh = (f16)v; f16 vl = (f16)(v - (float)vh);
                int off = r * KPB + ((k * 2) ^ ((r & 7) << 4));
                *(f16*)((char*)smh + off) = vh;
                *(f16*)((char*)sml + off) = vl;
            }
        } else {
            // 64 rows x 96 halves; 6 threads/row, 16 halves (2x uint4) each
            int r  = tid / 6;
            int k0 = (tid - r * 6) * 16;
            const f16* src = ys + ((size_t)tt * B_TOTAL + row0 + r) * H + k0;
            uint4 v0 = *(const uint4*)(src);
            uint4 v1 = *(const uint4*)(src + 8);
            int swz = (r & 7) << 4;
            *(uint4*)((char*)smh + r * KPB + (((k0 + 0) * 2) ^ swz)) = v0;
            *(uint4*)((char*)smh + r * KPB + (((k0 + 8) * 2) ^ swz)) = v1;
        }
    };

    __syncthreads();
    spin_ge(1);
    stage(0);
    __syncthreads();

    const int aswz = (j15 & 7) << 4;

#pragma unroll 1
    for (int t = 0; t < T_STEPS; ++t) {
        float h4[4][4];
        // ---- MFMA + register-local cell update, per m-tile (acc freed per m) ----
#pragma unroll
        for (int m = 0; m < 4; ++m) {
            f32x4 acch[4], accl[4];
#pragma unroll
            for (int q = 0; q < 4; ++q) {
                f32x4 a = {bq[q], bq[q], bq[q], bq[q]}; acch[q] = a;
                f32x4 z = {0.f, 0.f, 0.f, 0.f};          accl[q] = z;
            }
            const int abase = (m * 16 + j15) * KPB;
#pragma unroll
            for (int s = 0; s < KS; ++s) {
                int kb = ((s * 64 + g4 * 16) ^ aswz);
                f16x8 ah = *(const f16x8*)((const char*)smh + abase + kb);
#pragma unroll
                for (int q = 0; q < 4; ++q)
                    acch[q] = __builtin_amdgcn_mfma_f32_16x16x32_f16(ah, Bf[q][s], acch[q], 0, 0, 0);
                if (s >= LO_S0) {
                    f16x8 al = *(const f16x8*)((const char*)sml + abase + kb);
#pragma unroll
                    for (int q = 0; q < 4; ++q)
                        accl[q] = __builtin_amdgcn_mfma_f32_16x16x32_f16(al, Bf[q][s], accl[q], 0, 0, 0);
                }
            }
#pragma unroll
            for (int r = 0; r < 4; ++r) {
                float iv = sigf(acch[0][r] + accl[0][r]);
                float fv = sigf(acch[1][r] + accl[1][r]);
                float gv = tanhf_(acch[2][r] + accl[2][r]);
                float ov = sigf(acch[3][r] + accl[3][r]);
                float c  = fv * c4[m][r] + iv * gv;
                c4[m][r] = c;
                h4[m][r] = ov * tanhf_(c);
            }
        }
        __syncthreads();   // all waves' LDS act reads done; writes may begin

#pragma unroll
        for (int m = 0; m < 4; ++m)
#pragma unroll
        for (int r = 0; r < 4; ++r) {
            int row = m * 16 + 4 * g4 + r;
            float h = h4[m][r];
            f16 hh = (f16)h;
            f16 hl = (f16)(h - (float)hh);
            int off = row * KPB + (((F + u) * 2) ^ ((row & 7) << 4));
            *(f16*)((char*)smh + off) = hh;
            *(f16*)((char*)sml + off) = hl;
            if (HAS_YSOUT) ys[((size_t)t * B_TOTAL + row0 + row) * H + u] = hh;
            if (hnout && t == T_STEPS - 1) hnout[(size_t)(row0 + row) * H + u] = h;
        }
        if (t + 1 < T_STEPS) { spin_ge(t + 2); stage(t + 1); }
        __syncthreads();   // LDS writes + ys stores drained before release
        if (HAS_YSOUT && tid == 0)
            __hip_atomic_store(flag_out, t + 1, __ATOMIC_RELEASE, __HIP_MEMORY_SCOPE_AGENT);
    }
}

__global__ __launch_bounds__(NTH, 2)   // cap 256 VGPR — the proven no-spill budget
void lstm_fused(const float* __restrict__ x,
                const float* __restrict__ W_ih0,
                const float* __restrict__ W_ih_rest,
                const float* __restrict__ W_hh,
                const float* __restrict__ b_ih,
                const float* __restrict__ b_hh,
                f16* __restrict__ ys, float* __restrict__ hn1, float* __restrict__ hn3,
                int* __restrict__ flags)
{
    __shared__ char smbase[SM_BYTES];
    const int l = blockIdx.x / NBPL;
    const int b = blockIdx.x - l * NBPL;
    const int GH = 384 * 96;
    int* f0 = flags + (0 * NBPL + b) * FLAG_STRIDE;
    int* f1 = flags + (1 * NBPL + b) * FLAG_STRIDE;
    int* f2 = flags + (2 * NBPL + b) * FLAG_STRIDE;

    if (l == 0)
        layer_body<24, 0, true,  true >(smbase, x, ys, W_ih0,              W_hh,          b_ih,           b_hh,           nullptr, nullptr, f0, b);
    else if (l == 1)
        layer_body<96, 3, false, true >(smbase, nullptr, ys, W_ih_rest,          W_hh + 1 * GH, b_ih + 1 * 384, b_hh + 1 * 384, hn1,     f0, f1, b);
    else if (l == 2)
        layer_body<96, 3, false, true >(smbase, nullptr, ys, W_ih_rest + 1 * GH, W_hh + 2 * GH, b_ih + 2 * 384, b_hh + 2 * 384, nullptr, f1, f2, b);
    else
        layer_body<96, 3, false, false>(smbase, nullptr, ys, W_ih_rest + 2 * GH, W_hh + 3 * GH, b_ih + 3 * 384, b_hh + 3 * 384, hn3,    f2, nullptr, b);
}

__global__ __launch_bounds__(256)
void head_kernel(const float* __restrict__ hn1, const float* __restrict__ hn3,
                 const float* __restrict__ fc1_w, const float* __restrict__ fc1_b,
                 const float* __restrict__ fc2_w, const float* __restrict__ fc2_b,
                 const float* __restrict__ fc3_w, const float* __restrict__ fc3_b,
                 float* __restrict__ out)
{
    int b = blockIdx.x * blockDim.x + threadIdx.x;
    if (b >= B_TOTAL) return;
    float z1[16];
#pragma unroll
    for (int j = 0; j < 16; ++j) z1[j] = fc1_b[j];
    for (int uu = 0; uu < H; ++uu) {
        float s = hn1[(size_t)b * H + uu] + hn3[(size_t)b * H + uu];
        s = fmaxf(s, 0.f);
#pragma unroll
        for (int j = 0; j < 16; ++j) z1[j] += fc1_w[j * H + uu] * s;
    }
#pragma unroll
    for (int j = 0; j < 16; ++j) z1[j] = fmaxf(z1[j], 0.f);
    float z2[8];
#pragma unroll
    for (int j = 0; j < 8; ++j) {
        float a = fc2_b[j];
#pragma unroll
        for (int uu = 0; uu < 16; ++uu) a += fc2_w[j * 16 + uu] * z1[uu];
        z2[j] = fmaxf(a, 0.f);
    }
    float a = fc3_b[0];
#pragma unroll
    for (int uu = 0; uu < 8; ++uu) a += fc3_w[uu] * z2[uu];
    out[b] = a;
}

extern "C" void kernel_launch(void* const* d_in, const int* in_sizes, int n_in,
                              void* d_out, int out_size, void* d_ws, size_t ws_size,
                              hipStream_t stream) {
    const float* x         = (const float*)d_in[0];
    const float* W_ih0     = (const float*)d_in[1];
    const float* W_ih_rest = (const float*)d_in[2];
    const float* W_hh      = (const float*)d_in[3];
    const float* b_ih      = (const float*)d_in[4];
    const float* b_hh      = (const float*)d_in[5];
    const float* fc1_w     = (const float*)d_in[6];
    const float* fc1_b     = (const float*)d_in[7];
    const float* fc2_w     = (const float*)d_in[8];
    const float* fc2_b     = (const float*)d_in[9];
    const float* fc3_w     = (const float*)d_in[10];
    const float* fc3_b     = (const float*)d_in[11];
    float* out = (float*)d_out;

    const size_t YS = (size_t)T_STEPS * B_TOTAL * H * sizeof(f16);   // ~100.7 MB
    const size_t HN = (size_t)B_TOTAL * H * sizeof(float);           // ~1.6 MB
    const size_t FL = (size_t)3 * NBPL * FLAG_STRIDE * sizeof(int);  // 12 KB
    if (ws_size < YS + 2 * HN + FL) {
        hipMemsetAsync(d_out, 0, (size_t)out_size * sizeof(float), stream);
        return;
    }
    f16*   ys    = (f16*)d_ws;
    float* hn1   = (float*)((char*)d_ws + YS);
    float* hn3   = hn1 + (size_t)B_TOTAL * H;
    int*   flags = (int*)((char*)d_ws + YS + 2 * HN);

    hipMemsetAsync(flags, 0, FL, stream);

    lstm_fused<<<dim3(4 * NBPL), dim3(NTH), 0, stream>>>(
        x, W_ih0, W_ih_rest, W_hh, b_ih, b_hh, ys, hn1, hn3, flags);

    head_kernel<<<(B_TOTAL + 255) / 256, 256, 0, stream>>>(
        hn1, hn3, fc1_w, fc1_b, fc2_w, fc2_b, fc3_w, fc3_b, out);
}

// Round 6
// 2138.016 us; speedup vs baseline: 4.3694x; 1.8740x over previous
//
#include <hip/hip_runtime.h>
#include <math.h>

typedef _Float16 f16;
typedef _Float16 f16x8 __attribute__((ext_vector_type(8)));
typedef float f32x4 __attribute__((ext_vector_type(4)));

#define B_TOTAL 4096
#define T_STEPS 128
#define H 96
#define NB 64                 // batch rows per block (4 MFMA m-tiles)
#define NTH 384               // 6 waves
#define NBPL (B_TOTAL / NB)   // 64 blocks per layer; 4*64 = 256 = 1 block/CU
#define FLAG_STRIDE 16        // ints; one 64B line per flag
#define SM_BYTES 49152        // 2 planes * 64 rows * 192 * 2B (max KP)

__device__ __forceinline__ float sigf(float v) { return 1.f / (1.f + __expf(-v)); }
__device__ __forceinline__ float tanhf_(float v) { float e = __expf(2.f * v); return 1.f - 2.f / (e + 1.f); }

// One LSTM layer, persistent over all T, weights VGPR-resident as MFMA B-frags.
// 4-layer software pipeline across blocks. Producer->consumer sync per
// (link, batch-tile): producer releases flag=t+1 (agent scope) after ys[t]
// stores; consumer polls RELAXED on ONE thread (no per-poll cache
// invalidation!), then one acquire fence per step. ys is an in-place relay.
// LO_S0: first k-slice where the lo (residual) activation plane is nonzero;
// input-region lo slices of layers 1..3 are exactly zero (ys is pure f16).
template<int F, int LO_S0, bool IS_L0, bool HAS_YSOUT>
__device__ __forceinline__ void layer_body(
    char* smbase,
    const float* __restrict__ x32,
    f16*  __restrict__ ys,
    const float* __restrict__ Wi, const float* __restrict__ Wh,
    const float* __restrict__ bi, const float* __restrict__ bh,
    float* __restrict__ hnout,
    int* flag_in, int* flag_out, int b)
{
    constexpr int KS  = (F + H + 31) / 32;   // 4 (F=24) or 6 (F=96)
    constexpr int KP  = KS * 32;
    constexpr int KPB = KP * 2;

    f16* smh = (f16*)smbase;
    f16* sml = (f16*)(smbase + NB * KPB);

    const int tid  = threadIdx.x;
    const int lane = tid & 63;
    const int w    = tid >> 6;      // wave -> unit group
    const int j15  = lane & 15;
    const int g4   = lane >> 4;
    const int u    = 16 * w + j15;  // unit 0..95
    const int row0 = b * NB;

    for (int i = tid; i < NB * KP; i += NTH) { smh[i] = (f16)0.f; sml[i] = (f16)0.f; }

    // weight B-frags, loaded once: lane holds W[j=96q+u][k=32s+8*g4+e]
    f16x8 Bf[4][KS];
#pragma unroll
    for (int q = 0; q < 4; ++q) {
        const int j = 96 * q + u;
#pragma unroll
        for (int s = 0; s < KS; ++s) {
            f16x8 f;
#pragma unroll
            for (int e = 0; e < 8; ++e) {
                int k = 32 * s + 8 * g4 + e;
                float v = 0.f;
                if (k < F)          v = Wi[(size_t)j * F + k];
                else if (k - F < H) v = Wh[(size_t)j * H + (k - F)];
                f[e] = (f16)v;
            }
            Bf[q][s] = f;
        }
    }
    float bq[4];
#pragma unroll
    for (int q = 0; q < 4; ++q) bq[q] = bi[96 * q + u] + bh[96 * q + u];

    float c4[4][4];
#pragma unroll
    for (int m = 0; m < 4; ++m)
#pragma unroll
        for (int r = 0; r < 4; ++r) c4[m][r] = 0.f;

    // Wait until flag_in >= v. Single relaxed poller (no cache-invalidate
    // storm); one acquire fence per step for all threads after the barrier.
    auto spin_ge = [&](int v) {
        if constexpr (!IS_L0) {
            if (tid == 0) {
                while (__hip_atomic_load(flag_in, __ATOMIC_RELAXED, __HIP_MEMORY_SCOPE_AGENT) < v)
                    __builtin_amdgcn_s_sleep(8);
            }
            __syncthreads();
            __builtin_amdgcn_fence(__ATOMIC_ACQUIRE, "agent");
        }
    };
    auto stage = [&](int tt) {
        if constexpr (IS_L0) {
            // 64 rows x 24 feats = 1536 fp32; 4 per thread, stride-NTH (coalesced)
#pragma unroll
            for (int ii = 0; ii < 4; ++ii) {
                int i = tid + ii * NTH;
                int r = i / F, k = i - r * F;
                float v = x32[(size_t)(row0 + r) * (T_STEPS * F) + (size_t)tt * F + k];
                f16 vh = (f16)v; f16 vl = (f16)(v - (float)vh);
                int off = r * KPB + ((k * 2) ^ ((r & 7) << 4));
                *(f16*)((char*)smh + off) = vh;
                *(f16*)((char*)sml + off) = vl;
            }
        } else {
            // 64 rows x 96 halves; 6 threads/row, 16 halves (2x uint4) each
            int r  = tid / 6;
            int k0 = (tid - r * 6) * 16;
            const f16* src = ys + ((size_t)tt * B_TOTAL + row0 + r) * H + k0;
            uint4 v0 = *(const uint4*)(src);
            uint4 v1 = *(const uint4*)(src + 8);
            int swz = (r & 7) << 4;
            *(uint4*)((char*)smh + r * KPB + (((k0 + 0) * 2) ^ swz)) = v0;
            *(uint4*)((char*)smh + r * KPB + (((k0 + 8) * 2) ^ swz)) = v1;
        }
    };

    __syncthreads();
    spin_ge(1);
    stage(0);
    __syncthreads();

    const int aswz = (j15 & 7) << 4;

#pragma unroll 1
    for (int t = 0; t < T_STEPS; ++t) {
        float h4[4][4];
        // ---- MFMA + register-local cell update, per m-tile (acc freed per m) ----
#pragma unroll
        for (int m = 0; m < 4; ++m) {
            f32x4 acch[4], accl[4];
#pragma unroll
            for (int q = 0; q < 4; ++q) {
                f32x4 a = {bq[q], bq[q], bq[q], bq[q]}; acch[q] = a;
                f32x4 z = {0.f, 0.f, 0.f, 0.f};          accl[q] = z;
            }
            const int abase = (m * 16 + j15) * KPB;
#pragma unroll
            for (int s = 0; s < KS; ++s) {
                int kb = ((s * 64 + g4 * 16) ^ aswz);
                f16x8 ah = *(const f16x8*)((const char*)smh + abase + kb);
#pragma unroll
                for (int q = 0; q < 4; ++q)
                    acch[q] = __builtin_amdgcn_mfma_f32_16x16x32_f16(ah, Bf[q][s], acch[q], 0, 0, 0);
                if (s >= LO_S0) {
                    f16x8 al = *(const f16x8*)((const char*)sml + abase + kb);
#pragma unroll
                    for (int q = 0; q < 4; ++q)
                        accl[q] = __builtin_amdgcn_mfma_f32_16x16x32_f16(al, Bf[q][s], accl[q], 0, 0, 0);
                }
            }
#pragma unroll
            for (int r = 0; r < 4; ++r) {
                float iv = sigf(acch[0][r] + accl[0][r]);
                float fv = sigf(acch[1][r] + accl[1][r]);
                float gv = tanhf_(acch[2][r] + accl[2][r]);
                float ov = sigf(acch[3][r] + accl[3][r]);
                float c  = fv * c4[m][r] + iv * gv;
                c4[m][r] = c;
                h4[m][r] = ov * tanhf_(c);
            }
        }
        __syncthreads();   // all waves' LDS act reads done; writes may begin

#pragma unroll
        for (int m = 0; m < 4; ++m)
#pragma unroll
        for (int r = 0; r < 4; ++r) {
            int row = m * 16 + 4 * g4 + r;
            float h = h4[m][r];
            f16 hh = (f16)h;
            f16 hl = (f16)(h - (float)hh);
            int off = row * KPB + (((F + u) * 2) ^ ((row & 7) << 4));
            *(f16*)((char*)smh + off) = hh;
            *(f16*)((char*)sml + off) = hl;
            if (HAS_YSOUT) ys[((size_t)t * B_TOTAL + row0 + row) * H + u] = hh;
            if (hnout && t == T_STEPS - 1) hnout[(size_t)(row0 + row) * H + u] = h;
        }
        if (t + 1 < T_STEPS) { spin_ge(t + 2); stage(t + 1); }
        __syncthreads();   // LDS writes + ys stores drained before release
        if (HAS_YSOUT && tid == 0)
            __hip_atomic_store(flag_out, t + 1, __ATOMIC_RELEASE, __HIP_MEMORY_SCOPE_AGENT);
    }
}

__global__ __launch_bounds__(NTH, 2)   // cap 256 VGPR — the proven no-spill budget
void lstm_fused(const float* __restrict__ x,
                const float* __restrict__ W_ih0,
                const float* __restrict__ W_ih_rest,
                const float* __restrict__ W_hh,
                const float* __restrict__ b_ih,
                const float* __restrict__ b_hh,
                f16* __restrict__ ys, float* __restrict__ hn1, float* __restrict__ hn3,
                int* __restrict__ flags)
{
    __shared__ char smbase[SM_BYTES];
    const int l = blockIdx.x / NBPL;
    const int b = blockIdx.x - l * NBPL;
    const int GH = 384 * 96;
    int* f0 = flags + (0 * NBPL + b) * FLAG_STRIDE;
    int* f1 = flags + (1 * NBPL + b) * FLAG_STRIDE;
    int* f2 = flags + (2 * NBPL + b) * FLAG_STRIDE;

    if (l == 0)
        layer_body<24, 0, true,  true >(smbase, x, ys, W_ih0,              W_hh,          b_ih,           b_hh,           nullptr, nullptr, f0, b);
    else if (l == 1)
        layer_body<96, 3, false, true >(smbase, nullptr, ys, W_ih_rest,          W_hh + 1 * GH, b_ih + 1 * 384, b_hh + 1 * 384, hn1,     f0, f1, b);
    else if (l == 2)
        layer_body<96, 3, false, true >(smbase, nullptr, ys, W_ih_rest + 1 * GH, W_hh + 2 * GH, b_ih + 2 * 384, b_hh + 2 * 384, nullptr, f1, f2, b);
    else
        layer_body<96, 3, false, false>(smbase, nullptr, ys, W_ih_rest + 2 * GH, W_hh + 3 * GH, b_ih + 3 * 384, b_hh + 3 * 384, hn3,    f2, nullptr, b);
}

__global__ __launch_bounds__(256)
void head_kernel(const float* __restrict__ hn1, const float* __restrict__ hn3,
                 const float* __restrict__ fc1_w, const float* __restrict__ fc1_b,
                 const float* __restrict__ fc2_w, const float* __restrict__ fc2_b,
                 const float* __restrict__ fc3_w, const float* __restrict__ fc3_b,
                 float* __restrict__ out)
{
    int b = blockIdx.x * blockDim.x + threadIdx.x;
    if (b >= B_TOTAL) return;
    float z1[16];
#pragma unroll
    for (int j = 0; j < 16; ++j) z1[j] = fc1_b[j];
    for (int uu = 0; uu < H; ++uu) {
        float s = hn1[(size_t)b * H + uu] + hn3[(size_t)b * H + uu];
        s = fmaxf(s, 0.f);
#pragma unroll
        for (int j = 0; j < 16; ++j) z1[j] += fc1_w[j * H + uu] * s;
    }
#pragma unroll
    for (int j = 0; j < 16; ++j) z1[j] = fmaxf(z1[j], 0.f);
    float z2[8];
#pragma unroll
    for (int j = 0; j < 8; ++j) {
        float a = fc2_b[j];
#pragma unroll
        for (int uu = 0; uu < 16; ++uu) a += fc2_w[j * 16 + uu] * z1[uu];
        z2[j] = fmaxf(a, 0.f);
    }
    float a = fc3_b[0];
#pragma unroll
    for (int uu = 0; uu < 8; ++uu) a += fc3_w[uu] * z2[uu];
    out[b] = a;
}

extern "C" void kernel_launch(void* const* d_in, const int* in_sizes, int n_in,
                              void* d_out, int out_size, void* d_ws, size_t ws_size,
                              hipStream_t stream) {
    const float* x         = (const float*)d_in[0];
    const float* W_ih0     = (const float*)d_in[1];
    const float* W_ih_rest = (const float*)d_in[2];
    const float* W_hh      = (const float*)d_in[3];
    const float* b_ih      = (const float*)d_in[4];
    const float* b_hh      = (const float*)d_in[5];
    const float* fc1_w     = (const float*)d_in[6];
    const float* fc1_b     = (const float*)d_in[7];
    const float* fc2_w     = (const float*)d_in[8];
    const float* fc2_b     = (const float*)d_in[9];
    const float* fc3_w     = (const float*)d_in[10];
    const float* fc3_b     = (const float*)d_in[11];
    float* out = (float*)d_out;

    const size_t YS = (size_t)T_STEPS * B_TOTAL * H * sizeof(f16);   // ~100.7 MB
    const size_t HN = (size_t)B_TOTAL * H * sizeof(float);           // ~1.6 MB
    const size_t FL = (size_t)3 * NBPL * FLAG_STRIDE * sizeof(int);  // 12 KB
    if (ws_size < YS + 2 * HN + FL) {
        hipMemsetAsync(d_out, 0, (size_t)out_size * sizeof(float), stream);
        return;
    }
    f16*   ys    = (f16*)d_ws;
    float* hn1   = (float*)((char*)d_ws + YS);
    float* hn3   = hn1 + (size_t)B_TOTAL * H;
    int*   flags = (int*)((char*)d_ws + YS + 2 * HN);

    hipMemsetAsync(flags, 0, FL, stream);

    lstm_fused<<<dim3(4 * NBPL), dim3(NTH), 0, stream>>>(
        x, W_ih0, W_ih_rest, W_hh, b_ih, b_hh, ys, hn1, hn3, flags);

    head_kernel<<<(B_TOTAL + 255) / 256, 256, 0, stream>>>(
        hn1, hn3, fc1_w, fc1_b, fc2_w, fc2_b, fc3_w, fc3_b, out);
}

// Round 7
// 1882.342 us; speedup vs baseline: 4.9629x; 1.1358x over previous
//
#include <hip/hip_runtime.h>
#include <math.h>

typedef _Float16 f16;
typedef _Float16 f16x8 __attribute__((ext_vector_type(8)));
typedef float f32x4 __attribute__((ext_vector_type(4)));

#define B_TOTAL 4096
#define T_STEPS 128
#define H 96
#define NB 64                 // batch rows per block (4 MFMA m-tiles)
#define NTH 384               // 6 waves
#define NBPL (B_TOTAL / NB)   // 64 blocks per layer; 4*64 = 256 = 1 block/CU
#define FLAG_STRIDE 16        // ints; one 64B line per flag
#define SM_BYTES 49152        // 2 planes * 64 rows * 192 * 2B (max KP)

__device__ __forceinline__ float sigf(float v) { return 1.f / (1.f + __expf(-v)); }
__device__ __forceinline__ float tanhf_(float v) { float e = __expf(2.f * v); return 1.f - 2.f / (e + 1.f); }

// Fence-free cross-XCD relay: ALL ys accesses are agent-scope RELAXED atomics
// (coherent at L3, write-through, never dirty in any L1/L2), so no
// release/acquire cache maintenance (buffer_wbl2 / buffer_inv) is needed.
// Producer ordering: elementwise atomic ys stores -> __syncthreads (drains
// each wave's vmcnt => stores globally visible) -> tid0 RELAXED flag store.
// Consumer: tid0 RELAXED poll -> __syncthreads -> RELAXED atomic ys loads.
template<int F, int LO_S0, bool IS_L0, bool HAS_YSOUT>
__device__ __forceinline__ void layer_body(
    char* smbase,
    const float* __restrict__ x32,
    f16*  __restrict__ ys,
    const float* __restrict__ Wi, const float* __restrict__ Wh,
    const float* __restrict__ bi, const float* __restrict__ bh,
    float* __restrict__ hnout,
    int* flag_in, int* flag_out, int b)
{
    constexpr int KS  = (F + H + 31) / 32;   // 4 (F=24) or 6 (F=96)
    constexpr int KP  = KS * 32;
    constexpr int KPB = KP * 2;

    f16* smh = (f16*)smbase;
    f16* sml = (f16*)(smbase + NB * KPB);

    const int tid  = threadIdx.x;
    const int lane = tid & 63;
    const int w    = tid >> 6;      // wave -> unit group
    const int j15  = lane & 15;
    const int g4   = lane >> 4;
    const int u    = 16 * w + j15;  // unit 0..95
    const int row0 = b * NB;

    for (int i = tid; i < NB * KP; i += NTH) { smh[i] = (f16)0.f; sml[i] = (f16)0.f; }

    // weight B-frags, loaded once: lane holds W[j=96q+u][k=32s+8*g4+e]
    f16x8 Bf[4][KS];
#pragma unroll
    for (int q = 0; q < 4; ++q) {
        const int j = 96 * q + u;
#pragma unroll
        for (int s = 0; s < KS; ++s) {
            f16x8 f;
#pragma unroll
            for (int e = 0; e < 8; ++e) {
                int k = 32 * s + 8 * g4 + e;
                float v = 0.f;
                if (k < F)          v = Wi[(size_t)j * F + k];
                else if (k - F < H) v = Wh[(size_t)j * H + (k - F)];
                f[e] = (f16)v;
            }
            Bf[q][s] = f;
        }
    }
    float bq[4];
#pragma unroll
    for (int q = 0; q < 4; ++q) bq[q] = bi[96 * q + u] + bh[96 * q + u];

    float c4[4][4];
#pragma unroll
    for (int m = 0; m < 4; ++m)
#pragma unroll
        for (int r = 0; r < 4; ++r) c4[m][r] = 0.f;

    // Single relaxed poller; NO acquire fence (data path is itself coherent).
    auto spin_ge = [&](int v) {
        if constexpr (!IS_L0) {
            if (tid == 0) {
                while (__hip_atomic_load(flag_in, __ATOMIC_RELAXED, __HIP_MEMORY_SCOPE_AGENT) < v)
                    __builtin_amdgcn_s_sleep(2);
            }
            __syncthreads();
        }
    };
    auto stage = [&](int tt) {
        if constexpr (IS_L0) {
            // 64 rows x 24 feats = 1536 fp32; 4 per thread (plain cached loads:
            // x is read-only input, no coherence concern)
#pragma unroll
            for (int ii = 0; ii < 4; ++ii) {
                int i = tid + ii * NTH;
                int r = i / F, k = i - r * F;
                float v = x32[(size_t)(row0 + r) * (T_STEPS * F) + (size_t)tt * F + k];
                f16 vh = (f16)v; f16 vl = (f16)(v - (float)vh);
                int off = r * KPB + ((k * 2) ^ ((r & 7) << 4));
                *(f16*)((char*)smh + off) = vh;
                *(f16*)((char*)sml + off) = vl;
            }
        } else {
            // 64 rows x 96 halves; 6 threads/row, 16 halves each via 4x 8B
            // agent-scope RELAXED atomic loads (coherent read from L3)
            int r  = tid / 6;
            int k0 = (tid - r * 6) * 16;
            const unsigned long long* src =
                (const unsigned long long*)(ys + ((size_t)tt * B_TOTAL + row0 + r) * H + k0);
            unsigned long long a0 = __hip_atomic_load(src + 0, __ATOMIC_RELAXED, __HIP_MEMORY_SCOPE_AGENT);
            unsigned long long a1 = __hip_atomic_load(src + 1, __ATOMIC_RELAXED, __HIP_MEMORY_SCOPE_AGENT);
            unsigned long long a2 = __hip_atomic_load(src + 2, __ATOMIC_RELAXED, __HIP_MEMORY_SCOPE_AGENT);
            unsigned long long a3 = __hip_atomic_load(src + 3, __ATOMIC_RELAXED, __HIP_MEMORY_SCOPE_AGENT);
            int swz = (r & 7) << 4;
            char* base = (char*)smh + r * KPB;
            *(unsigned long long*)(base + (((k0 +  0) * 2) ^ swz)) = a0;
            *(unsigned long long*)(base + (((k0 +  4) * 2) ^ swz)) = a1;
            *(unsigned long long*)(base + (((k0 +  8) * 2) ^ swz)) = a2;
            *(unsigned long long*)(base + (((k0 + 12) * 2) ^ swz)) = a3;
        }
    };

    __syncthreads();
    spin_ge(1);
    stage(0);
    __syncthreads();

    const int aswz = (j15 & 7) << 4;

#pragma unroll 1
    for (int t = 0; t < T_STEPS; ++t) {
        float h4[4][4];
        // ---- MFMA + register-local cell update, per m-tile (acc freed per m) ----
#pragma unroll
        for (int m = 0; m < 4; ++m) {
            f32x4 acch[4], accl[4];
#pragma unroll
            for (int q = 0; q < 4; ++q) {
                f32x4 a = {bq[q], bq[q], bq[q], bq[q]}; acch[q] = a;
                f32x4 z = {0.f, 0.f, 0.f, 0.f};          accl[q] = z;
            }
            const int abase = (m * 16 + j15) * KPB;
#pragma unroll
            for (int s = 0; s < KS; ++s) {
                int kb = ((s * 64 + g4 * 16) ^ aswz);
                f16x8 ah = *(const f16x8*)((const char*)smh + abase + kb);
#pragma unroll
                for (int q = 0; q < 4; ++q)
                    acch[q] = __builtin_amdgcn_mfma_f32_16x16x32_f16(ah, Bf[q][s], acch[q], 0, 0, 0);
                if (s >= LO_S0) {
                    f16x8 al = *(const f16x8*)((const char*)sml + abase + kb);
#pragma unroll
                    for (int q = 0; q < 4; ++q)
                        accl[q] = __builtin_amdgcn_mfma_f32_16x16x32_f16(al, Bf[q][s], accl[q], 0, 0, 0);
                }
            }
#pragma unroll
            for (int r = 0; r < 4; ++r) {
                float iv = sigf(acch[0][r] + accl[0][r]);
                float fv = sigf(acch[1][r] + accl[1][r]);
                float gv = tanhf_(acch[2][r] + accl[2][r]);
                float ov = sigf(acch[3][r] + accl[3][r]);
                float c  = fv * c4[m][r] + iv * gv;
                c4[m][r] = c;
                h4[m][r] = ov * tanhf_(c);
            }
        }
        __syncthreads();   // all waves' LDS act reads done; writes may begin

#pragma unroll
        for (int m = 0; m < 4; ++m)
#pragma unroll
        for (int r = 0; r < 4; ++r) {
            int row = m * 16 + 4 * g4 + r;
            float h = h4[m][r];
            f16 hh = (f16)h;
            f16 hl = (f16)(h - (float)hh);
            int off = row * KPB + (((F + u) * 2) ^ ((row & 7) << 4));
            *(f16*)((char*)smh + off) = hh;
            *(f16*)((char*)sml + off) = hl;
            if (HAS_YSOUT) {
                // agent-scope RELAXED atomic store: write-through coherent,
                // leaves no dirty L1/L2 line -> no release fence needed
                unsigned short bits = __builtin_bit_cast(unsigned short, hh);
                __hip_atomic_store(
                    (unsigned short*)&ys[((size_t)t * B_TOTAL + row0 + row) * H + u],
                    bits, __ATOMIC_RELAXED, __HIP_MEMORY_SCOPE_AGENT);
            }
            if (hnout && t == T_STEPS - 1) hnout[(size_t)(row0 + row) * H + u] = h;
        }
        if (t + 1 < T_STEPS) { spin_ge(t + 2); stage(t + 1); }
        __syncthreads();   // per-wave vmcnt(0) drain => ys[t] globally visible
        if (HAS_YSOUT && tid == 0)
            __hip_atomic_store(flag_out, t + 1, __ATOMIC_RELAXED, __HIP_MEMORY_SCOPE_AGENT);
    }
}

__global__ __launch_bounds__(NTH, 2)   // cap 256 VGPR — the proven no-spill budget
void lstm_fused(const float* __restrict__ x,
                const float* __restrict__ W_ih0,
                const float* __restrict__ W_ih_rest,
                const float* __restrict__ W_hh,
                const float* __restrict__ b_ih,
                const float* __restrict__ b_hh,
                f16* __restrict__ ys, float* __restrict__ hn1, float* __restrict__ hn3,
                int* __restrict__ flags)
{
    __shared__ char smbase[SM_BYTES];
    const int l = blockIdx.x / NBPL;
    const int b = blockIdx.x - l * NBPL;
    const int GH = 384 * 96;
    int* f0 = flags + (0 * NBPL + b) * FLAG_STRIDE;
    int* f1 = flags + (1 * NBPL + b) * FLAG_STRIDE;
    int* f2 = flags + (2 * NBPL + b) * FLAG_STRIDE;

    if (l == 0)
        layer_body<24, 0, true,  true >(smbase, x, ys, W_ih0,              W_hh,          b_ih,           b_hh,           nullptr, nullptr, f0, b);
    else if (l == 1)
        layer_body<96, 3, false, true >(smbase, nullptr, ys, W_ih_rest,          W_hh + 1 * GH, b_ih + 1 * 384, b_hh + 1 * 384, hn1,     f0, f1, b);
    else if (l == 2)
        layer_body<96, 3, false, true >(smbase, nullptr, ys, W_ih_rest + 1 * GH, W_hh + 2 * GH, b_ih + 2 * 384, b_hh + 2 * 384, nullptr, f1, f2, b);
    else
        layer_body<96, 3, false, false>(smbase, nullptr, ys, W_ih_rest + 2 * GH, W_hh + 3 * GH, b_ih + 3 * 384, b_hh + 3 * 384, hn3,    f2, nullptr, b);
}

__global__ __launch_bounds__(256)
void head_kernel(const float* __restrict__ hn1, const float* __restrict__ hn3,
                 const float* __restrict__ fc1_w, const float* __restrict__ fc1_b,
                 const float* __restrict__ fc2_w, const float* __restrict__ fc2_b,
                 const float* __restrict__ fc3_w, const float* __restrict__ fc3_b,
                 float* __restrict__ out)
{
    int b = blockIdx.x * blockDim.x + threadIdx.x;
    if (b >= B_TOTAL) return;
    float z1[16];
#pragma unroll
    for (int j = 0; j < 16; ++j) z1[j] = fc1_b[j];
    for (int uu = 0; uu < H; ++uu) {
        float s = hn1[(size_t)b * H + uu] + hn3[(size_t)b * H + uu];
        s = fmaxf(s, 0.f);
#pragma unroll
        for (int j = 0; j < 16; ++j) z1[j] += fc1_w[j * H + uu] * s;
    }
#pragma unroll
    for (int j = 0; j < 16; ++j) z1[j] = fmaxf(z1[j], 0.f);
    float z2[8];
#pragma unroll
    for (int j = 0; j < 8; ++j) {
        float a = fc2_b[j];
#pragma unroll
        for (int uu = 0; uu < 16; ++uu) a += fc2_w[j * 16 + uu] * z1[uu];
        z2[j] = fmaxf(a, 0.f);
    }
    float a = fc3_b[0];
#pragma unroll
    for (int uu = 0; uu < 8; ++uu) a += fc3_w[uu] * z2[uu];
    out[b] = a;
}

extern "C" void kernel_launch(void* const* d_in, const int* in_sizes, int n_in,
                              void* d_out, int out_size, void* d_ws, size_t ws_size,
                              hipStream_t stream) {
    const float* x         = (const float*)d_in[0];
    const float* W_ih0     = (const float*)d_in[1];
    const float* W_ih_rest = (const float*)d_in[2];
    const float* W_hh      = (const float*)d_in[3];
    const float* b_ih      = (const float*)d_in[4];
    const float* b_hh      = (const float*)d_in[5];
    const float* fc1_w     = (const float*)d_in[6];
    const float* fc1_b     = (const float*)d_in[7];
    const float* fc2_w     = (const float*)d_in[8];
    const float* fc2_b     = (const float*)d_in[9];
    const float* fc3_w     = (const float*)d_in[10];
    const float* fc3_b     = (const float*)d_in[11];
    float* out = (float*)d_out;

    const size_t YS = (size_t)T_STEPS * B_TOTAL * H * sizeof(f16);   // ~100.7 MB
    const size_t HN = (size_t)B_TOTAL * H * sizeof(float);           // ~1.6 MB
    const size_t FL = (size_t)3 * NBPL * FLAG_STRIDE * sizeof(int);  // 12 KB
    if (ws_size < YS + 2 * HN + FL) {
        hipMemsetAsync(d_out, 0, (size_t)out_size * sizeof(float), stream);
        return;
    }
    f16*   ys    = (f16*)d_ws;
    float* hn1   = (float*)((char*)d_ws + YS);
    float* hn3   = hn1 + (size_t)B_TOTAL * H;
    int*   flags = (int*)((char*)d_ws + YS + 2 * HN);

    hipMemsetAsync(flags, 0, FL, stream);

    lstm_fused<<<dim3(4 * NBPL), dim3(NTH), 0, stream>>>(
        x, W_ih0, W_ih_rest, W_hh, b_ih, b_hh, ys, hn1, hn3, flags);

    head_kernel<<<(B_TOTAL + 255) / 256, 256, 0, stream>>>(
        hn1, hn3, fc1_w, fc1_b, fc2_w, fc2_b, fc3_w, fc3_b, out);
}